// Round 7
// baseline (269.699 us; speedup 1.0000x reference)
//
#include <hip/hip_runtime.h>
#include <hip/hip_bf16.h>
#include <cstdint>

#define NEG  (-1e30f)
#define VSZ  256      // vocab size (fixed for this problem)
#define TCAP 2048     // >= T = 2000 (fallback path)
#define LN2F 0.6931471805599453f

static __device__ __forceinline__ float    uifu(unsigned u) { return __uint_as_float(u); }
static __device__ __forceinline__ unsigned f2bf(float f) {   // f >= 0, finite; RTE
    unsigned u = __float_as_uint(f);
    return (u + 0x7fffu + ((u >> 16) & 1u)) >> 16;
}

// pack 2 f32 -> 2 bf16 (RNE) in one instruction; bit-identical to f2bf pair
static __device__ __forceinline__ unsigned pkbf(float lo, float hi) {
    unsigned r;
    asm("v_cvt_pk_bf16_f32 %0, %1, %2" : "=v"(r) : "v"(lo), "v"(hi));
    return r;
}

// canonical GCN wave64 sum reduction on the VALU pipe (no LDS bpermute)
static __device__ __forceinline__ float wave_sum_dpp(float v) {
    v += __int_as_float(__builtin_amdgcn_update_dpp(0, __float_as_int(v), 0x111, 0xf, 0xf, true));
    v += __int_as_float(__builtin_amdgcn_update_dpp(0, __float_as_int(v), 0x112, 0xf, 0xf, true));
    v += __int_as_float(__builtin_amdgcn_update_dpp(0, __float_as_int(v), 0x114, 0xf, 0xf, true));
    v += __int_as_float(__builtin_amdgcn_update_dpp(0, __float_as_int(v), 0x118, 0xf, 0xf, true));
    v += __int_as_float(__builtin_amdgcn_update_dpp(0, __float_as_int(v), 0x142, 0xa, 0xf, true));
    v += __int_as_float(__builtin_amdgcn_update_dpp(0, __float_as_int(v), 0x143, 0xc, 0xf, true));
    return __int_as_float(__builtin_amdgcn_readlane(__float_as_int(v), 63));
}

// ---------------------------------------------------------------------------
// Prep v7 (unchanged from R5): one wave per (b,t) row.
// ---------------------------------------------------------------------------
__global__ __launch_bounds__(256) void prep7(const float* __restrict__ logits,
                                             const int* __restrict__ targets,
                                             unsigned short* __restrict__ po,
                                             float* __restrict__ pbf,
                                             int T, int S) {
    const int b    = blockIdx.y;
    const int lane = threadIdx.x & 63;
    const int wv   = threadIdx.x >> 6;
    const int rt   = blockIdx.x * 4 + wv;
    if (rt >= T) return;
    const size_t row = (size_t)b * T + rt;
    __shared__ float ldse[4][VSZ];

    const float4* p = (const float4*)(logits + row * VSZ);
    float4 x = p[lane];
    float4 e;
    e.x = __expf(x.x); e.y = __expf(x.y); e.z = __expf(x.z); e.w = __expf(x.w);
    ((float4*)&ldse[wv][0])[lane] = e;

    float s  = (e.x + e.y) + (e.z + e.w);
    float tot = wave_sum_dpp(s);
    float rs  = __builtin_amdgcn_rcpf(tot);     // 1 ulp; output is bf16 anyway

    const int* tg = targets + (size_t)b * S;
    const int c0 = 4 * lane;
    uint2 st;
    if ((S & 3) == 0) {
        int4 tgv = *(const int4*)(tg + min(c0, S - 4));
        float g0 = ldse[wv][tgv.x] * rs;
        float g1 = ldse[wv][tgv.y] * rs;
        float g2 = ldse[wv][tgv.z] * rs;
        float g3 = ldse[wv][tgv.w] * rs;
        st.x = pkbf(g0, g1);
        st.y = pkbf(g2, g3);
    } else {
        float g0 = 0.f, g1 = 0.f, g2 = 0.f, g3 = 0.f;
        if (c0     < S) g0 = ldse[wv][tg[c0]]     * rs;
        if (c0 + 1 < S) g1 = ldse[wv][tg[c0 + 1]] * rs;
        if (c0 + 2 < S) g2 = ldse[wv][tg[c0 + 2]] * rs;
        if (c0 + 3 < S) g3 = ldse[wv][tg[c0 + 3]] * rs;
        st.x = pkbf(g0, g1);
        st.y = pkbf(g2, g3);
    }
    ((uint2*)(po + row * VSZ))[lane] = st;
    if (lane == 0) pbf[row] = e.x * rs;
}

// ---------------------------------------------------------------------------
// Scan v14: producer/consumer wave split. 256 threads = 4 waves:
//   w0 = fwd consumer, w1 = bwd consumer (pure VALU + ds_read; ZERO VMEM
//        instructions -> no vmcnt wait can exist in their code)
//   w2 = fwd producer, w3 = bwd producer (global_load_lds staging + vmcnt(0))
// One __syncthreads per 32-step window hands buffers over; producer stages
// window k+1 while consumer computes window k (disjoint double buffers).
// Producer staging (~1000cy incl. HBM drain) hides inside the consumer's
// ~2500cy window. Barrier counts uniform across waves via nwinMax from the
// block-uniform len. BODY/RENORM numerics identical to v9..v13.
// ---------------------------------------------------------------------------
typedef __attribute__((address_space(1))) unsigned int g1u_t;
typedef __attribute__((address_space(3))) unsigned int l3u_t;

static __device__ __forceinline__ void dma16(const void* g, void* l) {
    __builtin_amdgcn_global_load_lds((g1u_t*)(uintptr_t)g,
                                     (l3u_t*)(unsigned int)(uintptr_t)l, 16, 0, 0);
}
static __device__ __forceinline__ void dma4(const void* g, void* l) {
    __builtin_amdgcn_global_load_lds((g1u_t*)(uintptr_t)g,
                                     (l3u_t*)(unsigned int)(uintptr_t)l, 4, 0, 0);
}
static __device__ __forceinline__ float dpp_shr1_f(float v) {   // lane i <- i-1, lane0 -> 0
    return __int_as_float(__builtin_amdgcn_update_dpp(0, __float_as_int(v), 0x138, 0xf, 0xf, true));
}
static __device__ __forceinline__ float dpp_shl1_f(float v) {   // lane i <- i+1, lane63 -> 0
    return __int_as_float(__builtin_amdgcn_update_dpp(0, __float_as_int(v), 0x130, 0xf, 0xf, true));
}
static __device__ __forceinline__ int dpp_shr1_i(int v) {
    return __builtin_amdgcn_update_dpp(0, v, 0x138, 0xf, 0xf, true);
}
static __device__ __forceinline__ int dpp_shl1_i(int v) {
    return __builtin_amdgcn_update_dpp(0, v, 0x130, 0xf, 0xf, true);
}

#define ROWOF(t_) (W ? max(lm1 - (t_), 0) : min((t_), lm1))

// ---- producer: stage windows, one barrier per window -----------------------
template<int W>
static __device__ __forceinline__ void stage_dir(const unsigned short* __restrict__ po_b,
                                                 const float* __restrict__ pbr,
                                                 unsigned short* __restrict__ d0,
                                                 unsigned short* __restrict__ d1,
                                                 float* __restrict__ p0,
                                                 float* __restrict__ p1,
                                                 int lenD, int lm1, int i, int nwinMax) {
    const int  lhalf = i & 31;
    const bool hi    = (i >= 32);
    const int  nwin  = (lenD + 31) >> 5;

#define STAGE(DN, PN_, TBASE) { \
    _Pragma("unroll") \
    for (int u = 0; u < 32; u += 2) { \
        const int rA = ROWOF((TBASE) + u), rB = ROWOF((TBASE) + u + 1); \
        dma16(po_b + (size_t)(hi ? rB : rA) * VSZ + 8 * lhalf, (DN) + (size_t)u * VSZ); \
    } \
    dma4(pbr + ROWOF((TBASE) + lhalf), (PN_)); \
}

    STAGE(d0, p0, 0)
    asm volatile("s_waitcnt vmcnt(0)" ::: "memory");
    #pragma clang loop unroll(disable)
    for (int k = 0; k < nwinMax; ++k) {
        __syncthreads();                       // publish window k
        if (k + 1 < nwin) {
            unsigned short* DN = ((k + 1) & 1) ? d1 : d0;
            float*          PN = ((k + 1) & 1) ? p1 : p0;
            STAGE(DN, PN, 32 * (k + 1))
            asm volatile("s_waitcnt vmcnt(0)" ::: "memory");
        }
    }
#undef STAGE
}

// ---- consumer: pure VALU + ds_read ----------------------------------------
#define BODY(XV, PBV) { \
    float pA = uifu(XV.x << 16); \
    float pB = uifu(XV.x & 0xffff0000u); \
    float pC = uifu(XV.y << 16); \
    float pD = uifu(XV.y & 0xffff0000u); \
    if (W == 0) { \
        float hs = dpp_shr1_f(A[7]) * dscale; \
        float s7 = fmaf(m7, A[5], A[6]) + A[7]; \
        float s5 = fmaf(m5, A[3], A[4]) + A[5]; \
        float s3 = fmaf(m3, A[1], A[2]) + A[3]; \
        float s1 = fmaf(m1, hs,   A[0]) + A[1]; \
        A[7] = s7 * pD;  A[6] = (A[6] + A[5]) * (PBV); \
        A[5] = s5 * pC;  A[4] = (A[4] + A[3]) * (PBV); \
        A[3] = s3 * pB;  A[2] = (A[2] + A[1]) * (PBV); \
        A[1] = s1 * pA;  A[0] = (A[0] + hs)   * (PBV); \
    } else { \
        float q0 = A[0] * (PBV), q1 = A[1] * pA; \
        float q2 = A[2] * (PBV), q3 = A[3] * pB; \
        float q4 = A[4] * (PBV), q5 = A[5] * pC; \
        float q6 = A[6] * (PBV), q7 = A[7] * pD; \
        float nq0 = dpp_shl1_f(q0) * dscale; \
        float nq1 = dpp_shl1_f(q1) * dscale; \
        A[0] = q0 + q1; \
        A[1] = fmaf(m3, q3, q1 + q2); \
        A[2] = q2 + q3; \
        A[3] = fmaf(m5, q5, q3 + q4); \
        A[4] = q4 + q5; \
        A[5] = fmaf(m7, q7, q5 + q6); \
        A[6] = q6 + q7; \
        A[7] = fmaf(n7, nq1, q7 + nq0); \
    } \
}

#define RENORM { \
    float lmx = fmaxf(fmaxf(fmaxf(A[0], A[1]), fmaxf(A[2], A[3])), \
                      fmaxf(fmaxf(A[4], A[5]), fmaxf(A[6], A[7]))); \
    unsigned mb = __float_as_uint(lmx) >> 23; \
    mb = mb > 253u ? 253u : mb; \
    float sc_ = uifu((254u - mb) << 23); \
    A[0] *= sc_; A[1] *= sc_; A[2] *= sc_; A[3] *= sc_; \
    A[4] *= sc_; A[5] *= sc_; A[6] *= sc_; A[7] *= sc_; \
    E += (int)mb - 127; \
    int he = W ? dpp_shl1_i(E) : dpp_shr1_i(E); \
    int d  = min(max(he - E, -100), 100); \
    dscale = uifu((unsigned)(d + 127) << 23); \
}

#define LDB(R, QA, QB, DC, PC, BASE) { \
    R##0 = *(const uint2*)((DC) + (size_t)((BASE) + 0) * VSZ + 4 * i); \
    R##1 = *(const uint2*)((DC) + (size_t)((BASE) + 1) * VSZ + 4 * i); \
    R##2 = *(const uint2*)((DC) + (size_t)((BASE) + 2) * VSZ + 4 * i); \
    R##3 = *(const uint2*)((DC) + (size_t)((BASE) + 3) * VSZ + 4 * i); \
    R##4 = *(const uint2*)((DC) + (size_t)((BASE) + 4) * VSZ + 4 * i); \
    R##5 = *(const uint2*)((DC) + (size_t)((BASE) + 5) * VSZ + 4 * i); \
    R##6 = *(const uint2*)((DC) + (size_t)((BASE) + 6) * VSZ + 4 * i); \
    R##7 = *(const uint2*)((DC) + (size_t)((BASE) + 7) * VSZ + 4 * i); \
    QA = *(const float4*)((PC) + (BASE)); \
    QB = *(const float4*)((PC) + (BASE) + 4); \
}

#define CMP8(R, QA, QB) { \
    BODY(R##0, QA.x) BODY(R##1, QA.y) BODY(R##2, QA.z) BODY(R##3, QA.w) RENORM \
    BODY(R##4, QB.x) BODY(R##5, QB.y) BODY(R##6, QB.z) BODY(R##7, QB.w) RENORM \
}

#define SBAR __builtin_amdgcn_sched_barrier(0)

template<int W>
static __device__ __forceinline__ void scan_dir(const unsigned short* __restrict__ d0,
                                                const unsigned short* __restrict__ d1,
                                                const float* __restrict__ p0,
                                                const float* __restrict__ p1,
                                                int lenD, int i,
                                                float m1, float m3, float m5, float m7, float n7,
                                                float A[8], int& E, int nwinMax) {
    float dscale = 1.f;
    uint2 ra0, ra1, ra2, ra3, ra4, ra5, ra6, ra7;
    uint2 rb0, rb1, rb2, rb3, rb4, rb5, rb6, rb7;
    float4 qaA, qaB, qbA, qbB;
    const int nfull = lenD >> 5;
    const int ntail = lenD & 31;

    #pragma clang loop unroll(disable)
    for (int k = 0; k < nwinMax; ++k) {
        __syncthreads();                       // window k data ready
        const unsigned short* DC = (k & 1) ? d1 : d0;
        const float*          PC = (k & 1) ? p1 : p0;
        if (k < nfull) {
            LDB(ra, qaA, qaB, DC, PC, 0)
            SBAR;
            LDB(rb, qbA, qbB, DC, PC, 8)
            SBAR;
            CMP8(ra, qaA, qaB)
            LDB(ra, qaA, qaB, DC, PC, 16)
            SBAR;
            CMP8(rb, qbA, qbB)
            LDB(rb, qbA, qbB, DC, PC, 24)
            SBAR;
            CMP8(ra, qaA, qaB)
            CMP8(rb, qbA, qbB)
        } else if (k == nfull && ntail) {
            #pragma clang loop unroll(disable)
            for (int u = 0; u < ntail; ++u) {
                uint2 x = *(const uint2*)(DC + (size_t)u * VSZ + 4 * i);
                float pb = PC[u];
                BODY(x, pb)
                if ((u & 3) == 3) RENORM
            }
        }
    }
}

#undef SBAR
#undef CMP8
#undef LDB
#undef RENORM
#undef BODY
#undef ROWOF

__global__ __launch_bounds__(256, 1) void ctc_scan14(const unsigned short* __restrict__ po,
                                                     const float* __restrict__ pbf,
                                                     const int* __restrict__ targets,
                                                     const int* __restrict__ llen_p,
                                                     const int* __restrict__ tlen_p,
                                                     float* __restrict__ out,
                                                     int T, int S) {
    const int b   = blockIdx.x;
    const int w   = threadIdx.x >> 6;     // 0=fwd cons, 1=bwd cons, 2=fwd prod, 3=bwd prod
    const int i   = threadIdx.x & 63;
    const int len  = llen_p[b];
    const int lm1  = len - 1;
    const int lenF = (len + 1) >> 1;
    const int lenB = len - lenF;
    const int nwinF = (lenF + 31) >> 5;
    const int nwinB = (lenB + 31) >> 5;
    const int nwinMax = nwinF > nwinB ? nwinF : nwinB;

    __shared__ __align__(16) unsigned short dF0[32 * VSZ], dF1[32 * VSZ];
    __shared__ __align__(16) unsigned short dB0[32 * VSZ], dB1[32 * VSZ];
    __shared__ __align__(16) float pF0[64], pF1[64], pB0[64], pB1[64];
    __shared__ __align__(16) float bfin[512];
    __shared__ int bein[64];

    const unsigned short* po_b = po + (size_t)b * T * VSZ;
    const float*          pbr  = pbf + (size_t)b * T;

    float A[8];
    int   E = 0;

    if (w < 2) {
        // skip masks from targets (consumers only)
        const int* tg  = targets + (size_t)b * S;
        const int Sm1  = S - 1;
        const int j0   = 4 * i;
        const int tm   = tg[max(min(j0 - 1, Sm1), 0)];
        const int t0l  = tg[min(j0,     Sm1)];
        const int t1l  = tg[min(j0 + 1, Sm1)];
        const int t2l  = tg[min(j0 + 2, Sm1)];
        const int t3l  = tg[min(j0 + 3, Sm1)];
        const int t4l  = tg[min(j0 + 4, Sm1)];
        const float m1 = (j0 == 0 || t0l != tm) ? 1.f : 0.f;
        const float m3 = (t1l != t0l) ? 1.f : 0.f;
        const float m5 = (t2l != t1l) ? 1.f : 0.f;
        const float m7 = (t3l != t2l) ? 1.f : 0.f;
        const float n7 = (t4l != t3l) ? 1.f : 0.f;

        if (w == 0) {
            #pragma unroll
            for (int k = 0; k < 8; ++k) A[k] = 0.f;
            if (i == 0) A[0] = 1.f;                           // alpha init
            scan_dir<0>(dF0, dF1, pF0, pF1, lenF, i,
                        m1, m3, m5, m7, n7, A, E, nwinMax);
        } else {
            const int tl = tlen_p[b];
            const int s1 = 2 * tl - 1, s2 = 2 * tl;
            #pragma unroll
            for (int k = 0; k < 8; ++k)
                A[k] = (8 * i + k == s1 || 8 * i + k == s2) ? 1.f : 0.f;  // beta init
            scan_dir<1>(dB0, dB1, pB0, pB1, lenB, i,
                        m1, m3, m5, m7, n7, A, E, nwinMax);
        }
    } else if (w == 2) {
        stage_dir<0>(po_b, pbr, dF0, dF1, pF0, pF1, lenF, lm1, i, nwinMax);
    } else {
        stage_dir<1>(po_b, pbr, dB0, dB1, pB0, pB1, lenB, lm1, i, nwinMax);
    }

    if (w == 1) {
        *(float4*)&bfin[8 * i]     = make_float4(A[0], A[1], A[2], A[3]);
        *(float4*)&bfin[8 * i + 4] = make_float4(A[4], A[5], A[6], A[7]);
        bein[i] = E;
    }
    __syncthreads();
    if (w == 0) {
        // total = sum_s alpha_{m-1}[s] * beta_{m-1}[s], per-lane pow2 exponents
        float4 u0 = *(float4*)&bfin[8 * i];
        float4 u1 = *(float4*)&bfin[8 * i + 4];
        float dsum = A[0]*u0.x + A[1]*u0.y + A[2]*u0.z + A[3]*u0.w
                   + A[4]*u1.x + A[5]*u1.y + A[6]*u1.z + A[7]*u1.w;
        float li = (dsum > 0.f) ? __logf(dsum) + (float)(E + bein[i]) * LN2F : NEG;
        float mx = li;
        #pragma unroll
        for (int off = 32; off; off >>= 1) mx = fmaxf(mx, __shfl_xor(mx, off, 64));
        float ss = __expf(li - mx);
        #pragma unroll
        for (int off = 32; off; off >>= 1) ss += __shfl_xor(ss, off, 64);
        if (i == 0) out[b] = -(mx + __logf(ss));
    }
}

// ---------------------------------------------------------------------------
// Fallback (R2, known-good) if workspace is too small.
// ---------------------------------------------------------------------------
__device__ __forceinline__ void barrier_lgkm() {
    __asm__ volatile("s_waitcnt lgkmcnt(0)\n\ts_barrier" ::: "memory");
}

__global__ __launch_bounds__(256) void lse_kernel(const float* __restrict__ logits,
                                                  float* __restrict__ lse,
                                                  int nrows) {
    int row = blockIdx.x * 4 + (threadIdx.x >> 6);
    if (row >= nrows) return;
    int lane = threadIdx.x & 63;
    const float4* p = (const float4*)(logits + (size_t)row * VSZ);
    float4 x = p[lane];
    float m = fmaxf(fmaxf(x.x, x.y), fmaxf(x.z, x.w));
    #pragma unroll
    for (int off = 32; off; off >>= 1) m = fmaxf(m, __shfl_xor(m, off, 64));
    float s = __expf(x.x - m) + __expf(x.y - m) + __expf(x.z - m) + __expf(x.w - m);
    #pragma unroll
    for (int off = 32; off; off >>= 1) s += __shfl_xor(s, off, 64);
    if (lane == 0) lse[row] = m + __logf(s);
}

__device__ __forceinline__ float lae(float a, float b) {
    float mx = fmaxf(a, b);
    float mn = fminf(a, b);
    return mx + __logf(1.0f + __expf(mn - mx));
}

__global__ __launch_bounds__(256, 1) void ctc_scan_fb(const float* __restrict__ logits,
                                                      const int* __restrict__ targets,
                                                      const int* __restrict__ llen_p,
                                                      const int* __restrict__ tlen_p,
                                                      const float* __restrict__ lse,
                                                      float* __restrict__ out,
                                                      int T, int S) {
    const int b = blockIdx.x;
    const int i = threadIdx.x;
    const int len = llen_p[b];

    __shared__ float blankv[TCAP];
    __shared__ float abuf[2][256 + 2];
    __shared__ float wsum[4];

    const float* __restrict__ lgb  = logits + (size_t)b * T * VSZ;
    const float* __restrict__ lseb = lse + (size_t)b * T;

    int  lab  = 0;
    bool skip = false;
    if (i < S) {
        lab = targets[b * S + i];
        int prev = (i >= 1) ? targets[b * S + i - 1] : -1;
        skip = (lab != prev);
    }
    for (int t = i; t < len; t += 256) blankv[t] = lgb[(size_t)t * VSZ];
    if (i < 2) abuf[i][0] = NEG;
    __syncthreads();

    float aEven = (i == 0) ? 0.0f : NEG;
    float aOdd  = NEG;
    const int lm1 = len - 1;
    float v0 = lgb[(size_t)lab];
    float v1 = lgb[(size_t)min(1, lm1) * VSZ + lab];
    float v2 = lgb[(size_t)min(2, lm1) * VSZ + lab];

    for (int t = 0; t < len; ++t) {
        float v3 = lgb[(size_t)min(t + 3, lm1) * VSZ + lab];
        float blv = blankv[t];
        abuf[t & 1][i + 1] = aOdd;
        barrier_lgkm();
        float nb = abuf[t & 1][i];
        float ne = lae(aEven, nb) + blv;
        float no = lae(lae(aOdd, aEven), skip ? nb : NEG) + v0;
        aEven = ne; aOdd = no;
        v0 = v1; v1 = v2; v2 = v3;
    }

    blankv[2 * i]     = aEven;
    blankv[2 * i + 1] = aOdd;
    float part = 0.f;
    for (int t = i; t < len; t += 256) part += lseb[t];
    #pragma unroll
    for (int off = 32; off; off >>= 1) part += __shfl_xor(part, off, 64);
    if ((i & 63) == 0) wsum[i >> 6] = part;
    __syncthreads();
    if (i == 0) {
        int tl = tlen_p[b];
        float s = wsum[0] + wsum[1] + wsum[2] + wsum[3];
        out[b] = s - lae(blankv[2 * tl - 1], blankv[2 * tl]);
    }
}

// ---------------------------------------------------------------------------
extern "C" void kernel_launch(void* const* d_in, const int* in_sizes, int n_in,
                              void* d_out, int out_size, void* d_ws, size_t ws_size,
                              hipStream_t stream) {
    const float* logits  = (const float*)d_in[0];
    const int*   targets = (const int*)d_in[1];
    const int*   llen    = (const int*)d_in[2];
    const int*   tlen    = (const int*)d_in[3];
    float*       out     = (float*)d_out;

    const int B = in_sizes[2];
    const int S = in_sizes[1] / B;
    const int T = in_sizes[0] / (B * VSZ);
    const int nrows = B * T;

    const size_t need = (size_t)nrows * VSZ * sizeof(unsigned short)
                      + (size_t)nrows * sizeof(float);
    if (ws_size >= need) {
        unsigned short* po = (unsigned short*)d_ws;            // nrows*256 bf16
        float* pbf = (float*)(po + (size_t)nrows * VSZ);       // nrows f32
        dim3 grid((T + 3) / 4, B);
        prep7<<<grid, 256, 0, stream>>>(logits, targets, po, pbf, T, S);
        ctc_scan14<<<B, 256, 0, stream>>>(po, pbf, targets, llen, tlen, out, T, S);
    } else {
        float* lse = (float*)d_ws;                             // nrows f32
        lse_kernel<<<(nrows + 3) / 4, 256, 0, stream>>>(logits, lse, nrows);
        ctc_scan_fb<<<B, 256, 0, stream>>>(logits, targets, llen, tlen, lse, out, T, S);
    }
}

// Round 8
// 250.913 us; speedup vs baseline: 1.0749x; 1.0749x over previous
//
#include <hip/hip_runtime.h>
#include <hip/hip_bf16.h>
#include <cstdint>

#define NEG  (-1e30f)
#define VSZ  256      // vocab size (fixed for this problem)
#define TCAP 2048     // >= T = 2000 (fallback path)
#define LN2F 0.6931471805599453f

typedef __attribute__((ext_vector_type(2))) float f32x2;

static __device__ __forceinline__ float    uifu(unsigned u) { return __uint_as_float(u); }
static __device__ __forceinline__ unsigned f2bf(float f) {   // f >= 0, finite; RTE
    unsigned u = __float_as_uint(f);
    return (u + 0x7fffu + ((u >> 16) & 1u)) >> 16;
}

// pack 2 f32 -> 2 bf16 (RNE) in one instruction; bit-identical to f2bf pair
static __device__ __forceinline__ unsigned pkbf(float lo, float hi) {
    unsigned r;
    asm("v_cvt_pk_bf16_f32 %0, %1, %2" : "=v"(r) : "v"(lo), "v"(hi));
    return r;
}

// canonical GCN wave64 sum reduction on the VALU pipe (no LDS bpermute)
static __device__ __forceinline__ float wave_sum_dpp(float v) {
    v += __int_as_float(__builtin_amdgcn_update_dpp(0, __float_as_int(v), 0x111, 0xf, 0xf, true));
    v += __int_as_float(__builtin_amdgcn_update_dpp(0, __float_as_int(v), 0x112, 0xf, 0xf, true));
    v += __int_as_float(__builtin_amdgcn_update_dpp(0, __float_as_int(v), 0x114, 0xf, 0xf, true));
    v += __int_as_float(__builtin_amdgcn_update_dpp(0, __float_as_int(v), 0x118, 0xf, 0xf, true));
    v += __int_as_float(__builtin_amdgcn_update_dpp(0, __float_as_int(v), 0x142, 0xa, 0xf, true));
    v += __int_as_float(__builtin_amdgcn_update_dpp(0, __float_as_int(v), 0x143, 0xc, 0xf, true));
    return __int_as_float(__builtin_amdgcn_readlane(__float_as_int(v), 63));
}

// ---------------------------------------------------------------------------
// Prep v7 (unchanged): one wave per (b,t) row.
// ---------------------------------------------------------------------------
__global__ __launch_bounds__(256) void prep7(const float* __restrict__ logits,
                                             const int* __restrict__ targets,
                                             unsigned short* __restrict__ po,
                                             float* __restrict__ pbf,
                                             int T, int S) {
    const int b    = blockIdx.y;
    const int lane = threadIdx.x & 63;
    const int wv   = threadIdx.x >> 6;
    const int rt   = blockIdx.x * 4 + wv;
    if (rt >= T) return;
    const size_t row = (size_t)b * T + rt;
    __shared__ float ldse[4][VSZ];

    const float4* p = (const float4*)(logits + row * VSZ);
    float4 x = p[lane];
    float4 e;
    e.x = __expf(x.x); e.y = __expf(x.y); e.z = __expf(x.z); e.w = __expf(x.w);
    ((float4*)&ldse[wv][0])[lane] = e;

    float s  = (e.x + e.y) + (e.z + e.w);
    float tot = wave_sum_dpp(s);
    float rs  = __builtin_amdgcn_rcpf(tot);     // 1 ulp; output is bf16 anyway

    const int* tg = targets + (size_t)b * S;
    const int c0 = 4 * lane;
    uint2 st;
    if ((S & 3) == 0) {
        int4 tgv = *(const int4*)(tg + min(c0, S - 4));
        float g0 = ldse[wv][tgv.x] * rs;
        float g1 = ldse[wv][tgv.y] * rs;
        float g2 = ldse[wv][tgv.z] * rs;
        float g3 = ldse[wv][tgv.w] * rs;
        st.x = pkbf(g0, g1);
        st.y = pkbf(g2, g3);
    } else {
        float g0 = 0.f, g1 = 0.f, g2 = 0.f, g3 = 0.f;
        if (c0     < S) g0 = ldse[wv][tg[c0]]     * rs;
        if (c0 + 1 < S) g1 = ldse[wv][tg[c0 + 1]] * rs;
        if (c0 + 2 < S) g2 = ldse[wv][tg[c0 + 2]] * rs;
        if (c0 + 3 < S) g3 = ldse[wv][tg[c0 + 3]] * rs;
        st.x = pkbf(g0, g1);
        st.y = pkbf(g2, g3);
    }
    ((uint2*)(po + row * VSZ))[lane] = st;
    if (lane == 0) pbf[row] = e.x * rs;
}

// ---------------------------------------------------------------------------
// Scan v15: v13 structure (self-staged DMA windows, branchless 32-step window,
// register-batch double-buffer, 1-block/CU pad) with the recurrence rewritten
// in PACKED f32 (VOP3P v_pk_fma/add/mul_f32 via <2 x float> ext-vectors).
// States pair at stride 4 -- P73=(A7,A3), P51=(A5,A1), E62=(A6,A2),
// E40=(A4,A0) -- making every recurrence op an aligned 2-wide op (one small
// (A3,hs) pack fwd; two packs bwd). Elementwise numerics IDENTICAL to the
// scalar v12/v13 code (same fma/add/mul per element, same max tree set,
// per-lane renorm + dscale exchange unchanged). Static VALU/step ~33 -> ~22.
// ---------------------------------------------------------------------------
typedef __attribute__((address_space(1))) unsigned int g1u_t;
typedef __attribute__((address_space(3))) unsigned int l3u_t;

static __device__ __forceinline__ void dma16(const void* g, void* l) {
    __builtin_amdgcn_global_load_lds((g1u_t*)(uintptr_t)g,
                                     (l3u_t*)(unsigned int)(uintptr_t)l, 16, 0, 0);
}
static __device__ __forceinline__ void dma4(const void* g, void* l) {
    __builtin_amdgcn_global_load_lds((g1u_t*)(uintptr_t)g,
                                     (l3u_t*)(unsigned int)(uintptr_t)l, 4, 0, 0);
}
static __device__ __forceinline__ float dpp_shr1_f(float v) {   // lane i <- i-1, lane0 -> 0
    return __int_as_float(__builtin_amdgcn_update_dpp(0, __float_as_int(v), 0x138, 0xf, 0xf, true));
}
static __device__ __forceinline__ float dpp_shl1_f(float v) {   // lane i <- i+1, lane63 -> 0
    return __int_as_float(__builtin_amdgcn_update_dpp(0, __float_as_int(v), 0x130, 0xf, 0xf, true));
}
static __device__ __forceinline__ int dpp_shr1_i(int v) {
    return __builtin_amdgcn_update_dpp(0, v, 0x138, 0xf, 0xf, true);
}
static __device__ __forceinline__ int dpp_shl1_i(int v) {
    return __builtin_amdgcn_update_dpp(0, v, 0x130, 0xf, 0xf, true);
}

// W = 0: forward alpha over frames [0, lenD). W = 1: backward beta consuming
// frames len-1 .. len-lenD (step t maps to frame lm1 - t).
template<int W>
static __device__ __forceinline__ void scan_dir(const unsigned short* __restrict__ po_b,
                                                const float* __restrict__ pbr,
                                                unsigned short* __restrict__ d0,
                                                unsigned short* __restrict__ d1,
                                                float* __restrict__ p0,
                                                float* __restrict__ p1,
                                                int lenD, int lm1, int i,
                                                float m1, float m3, float m5, float m7, float n7,
                                                float A[8], int& E) {
    const int  lhalf = i & 31;
    const bool hi    = (i >= 32);
    float dscale = 1.f;

    // packed state pairs (stride-4 pairing keeps all recurrence ops aligned)
    f32x2 P73, P51, E62, E40, M73, M51, N75;
    P73.x = A[7]; P73.y = A[3];
    P51.x = A[5]; P51.y = A[1];
    E62.x = A[6]; E62.y = A[2];
    E40.x = A[4]; E40.y = A[0];
    M73.x = m7;  M73.y = m3;
    M51.x = m5;  M51.y = m1;
    N75.x = n7;  N75.y = m5;

    // register batch double-buffer (named -> guaranteed VGPR residency)
    uint2 ra0, ra1, ra2, ra3, ra4, ra5, ra6, ra7;
    uint2 rb0, rb1, rb2, rb3, rb4, rb5, rb6, rb7;
    float4 qaA, qaB, qbA, qbB;

#define ROWOF(t_) (W ? max(lm1 - (t_), 0) : min((t_), lm1))

#define BODY(XV, PBV) { \
    f32x2 pDB, pCA, pbb; \
    pDB.x = uifu(XV.y & 0xffff0000u); pDB.y = uifu(XV.x & 0xffff0000u); \
    pCA.x = uifu(XV.y << 16);         pCA.y = uifu(XV.x << 16); \
    pbb.x = (PBV);                    pbb.y = (PBV); \
    if (W == 0) { \
        float hs = dpp_shr1_f(P73.x) * dscale; \
        f32x2 a3h; a3h.x = P73.y; a3h.y = hs; \
        f32x2 t73 = (__builtin_elementwise_fma(M73, P51, E62) + P73) * pDB; \
        f32x2 t51 = (__builtin_elementwise_fma(M51, a3h, E40) + P51) * pCA; \
        f32x2 t62 = (E62 + P51) * pbb; \
        f32x2 t40 = (E40 + a3h) * pbb; \
        P73 = t73; P51 = t51; E62 = t62; E40 = t40; \
    } else { \
        f32x2 Q73 = P73 * pDB, Q51 = P51 * pCA, Q62 = E62 * pbb, Q40 = E40 * pbb; \
        float nq0 = dpp_shl1_f(Q40.y) * dscale; \
        float nq1 = dpp_shl1_f(Q51.y) * dscale; \
        f32x2 nq04; nq04.x = nq0; nq04.y = Q40.x; \
        f32x2 n1q5; n1q5.x = nq1; n1q5.y = Q51.x; \
        f32x2 t73 = __builtin_elementwise_fma(N75, n1q5, Q73 + nq04); \
        f32x2 t51 = __builtin_elementwise_fma(M73, Q73, Q51 + Q62); \
        f32x2 t62 = Q62 + Q73; \
        f32x2 t40 = Q40 + Q51; \
        P73 = t73; P51 = t51; E62 = t62; E40 = t40; \
    } \
}

#define RENORM { \
    f32x2 mA = __builtin_elementwise_max(__builtin_elementwise_max(P73, P51), \
                                         __builtin_elementwise_max(E62, E40)); \
    float lmx = fmaxf(mA.x, mA.y); \
    unsigned mb = __float_as_uint(lmx) >> 23; \
    mb = mb > 253u ? 253u : mb; \
    float sc_ = uifu((254u - mb) << 23); \
    f32x2 scv; scv.x = sc_; scv.y = sc_; \
    P73 *= scv; P51 *= scv; E62 *= scv; E40 *= scv; \
    E += (int)mb - 127; \
    int he = W ? dpp_shl1_i(E) : dpp_shr1_i(E); \
    int d  = min(max(he - E, -100), 100); \
    dscale = uifu((unsigned)(d + 127) << 23); \
}

// stage window starting at frame-step TBASE into (DN, PN_): 16 data-DMAs
// (2 rows each) + 1 blank-DMA = 17 vmcnt ops
#define STAGE(DN, PN_, TBASE) { \
    _Pragma("unroll") \
    for (int u = 0; u < 32; u += 2) { \
        const int rA = ROWOF((TBASE) + u), rB = ROWOF((TBASE) + u + 1); \
        dma16(po_b + (size_t)(hi ? rB : rA) * VSZ + 8 * lhalf, (DN) + (size_t)u * VSZ); \
    } \
    dma4(pbr + ROWOF((TBASE) + lhalf), (PN_)); \
}

// load one 8-step batch into a named register set
#define LDB(R, QA, QB, DC, PC, BASE) { \
    R##0 = *(const uint2*)((DC) + (size_t)((BASE) + 0) * VSZ + 4 * i); \
    R##1 = *(const uint2*)((DC) + (size_t)((BASE) + 1) * VSZ + 4 * i); \
    R##2 = *(const uint2*)((DC) + (size_t)((BASE) + 2) * VSZ + 4 * i); \
    R##3 = *(const uint2*)((DC) + (size_t)((BASE) + 3) * VSZ + 4 * i); \
    R##4 = *(const uint2*)((DC) + (size_t)((BASE) + 4) * VSZ + 4 * i); \
    R##5 = *(const uint2*)((DC) + (size_t)((BASE) + 5) * VSZ + 4 * i); \
    R##6 = *(const uint2*)((DC) + (size_t)((BASE) + 6) * VSZ + 4 * i); \
    R##7 = *(const uint2*)((DC) + (size_t)((BASE) + 7) * VSZ + 4 * i); \
    QA = *(const float4*)((PC) + (BASE)); \
    QB = *(const float4*)((PC) + (BASE) + 4); \
}

// compute one 8-step batch from a named register set
#define CMP8(R, QA, QB) { \
    BODY(R##0, QA.x) BODY(R##1, QA.y) BODY(R##2, QA.z) BODY(R##3, QA.w) RENORM \
    BODY(R##4, QB.x) BODY(R##5, QB.y) BODY(R##6, QB.z) BODY(R##7, QB.w) RENORM \
}

#define SBAR __builtin_amdgcn_sched_barrier(0)

#define SUPERF(DC, PC, DN, PN_) { \
    STAGE(DN, PN_, t0 + 32) \
    asm volatile("s_waitcnt vmcnt(17)" ::: "memory"); \
    LDB(ra, qaA, qaB, DC, PC, 0) \
    SBAR; \
    LDB(rb, qbA, qbB, DC, PC, 8) \
    SBAR; \
    CMP8(ra, qaA, qaB) \
    LDB(ra, qaA, qaB, DC, PC, 16) \
    SBAR; \
    CMP8(rb, qbA, qbB) \
    LDB(rb, qbA, qbB, DC, PC, 24) \
    SBAR; \
    CMP8(ra, qaA, qaB) \
    CMP8(rb, qbA, qbB) \
}

    // prologue: stage window 0
    STAGE(d0, p0, 0)

    int t0 = 0;
    const int nfull = lenD >> 5;
    const int ntail = lenD & 31;
    unsigned short* cur = d0; unsigned short* nxt = d1;
    float* pc = p0;  float* pn = p1;

    #pragma clang loop unroll(disable)
    for (int sl = 0; sl < nfull; ++sl) {
        SUPERF(cur, pc, nxt, pn)
        t0 += 32;
        unsigned short* td = cur; cur = nxt; nxt = td;
        float* tp = pc; pc = pn; pn = tp;
    }
    if (ntail) {
        asm volatile("s_waitcnt vmcnt(0)" ::: "memory");
        #pragma clang loop unroll(disable)
        for (int u = 0; u < ntail; ++u) {
            uint2 x = *(const uint2*)(cur + (size_t)u * VSZ + 4 * i);
            float pb = pc[u];
            BODY(x, pb)
            if ((u & 3) == 3) RENORM
        }
    }

    // write state back to the scalar interface
    A[7] = P73.x; A[3] = P73.y;
    A[5] = P51.x; A[1] = P51.y;
    A[6] = E62.x; A[2] = E62.y;
    A[4] = E40.x; A[0] = E40.y;
#undef SUPERF
#undef SBAR
#undef CMP8
#undef LDB
#undef STAGE
#undef RENORM
#undef BODY
#undef ROWOF
}

__global__ __launch_bounds__(128, 1) void ctc_scan15(const unsigned short* __restrict__ po,
                                                     const float* __restrict__ pbf,
                                                     const int* __restrict__ targets,
                                                     const int* __restrict__ llen_p,
                                                     const int* __restrict__ tlen_p,
                                                     float* __restrict__ out,
                                                     int T, int S) {
    const int b   = blockIdx.x;
    const int w   = threadIdx.x >> 6;     // 0 = forward wave, 1 = backward wave
    const int i   = threadIdx.x & 63;
    const int len  = llen_p[b];
    const int lm1  = len - 1;
    const int lenF = (len + 1) >> 1;      // forward steps m
    const int lenD = w ? (len - lenF) : lenF;

    __shared__ __align__(16) unsigned short dF0[32 * VSZ], dF1[32 * VSZ];
    __shared__ __align__(16) unsigned short dB0[32 * VSZ], dB1[32 * VSZ];
    __shared__ __align__(16) float pF0[64], pF1[64], pB0[64], pB1[64];
    __shared__ __align__(16) float bfin[512];
    __shared__ int bein[64];
    // occupancy limiter: push LDS past 80 KiB so only ONE block fits per CU
    // (v13-measured best; co-residency neutral-to-slightly-negative).
    __shared__ __align__(16) unsigned char lds_pad[16384];
    if (__builtin_expect(T < 0, 0)) ((volatile unsigned char*)lds_pad)[0] = 1;

    // skip masks from targets (j0 = 4i covers odd states 8i+1,+3,+5,+7)
    const int* tg  = targets + (size_t)b * S;
    const int Sm1  = S - 1;
    const int j0   = 4 * i;
    const int tm   = tg[max(min(j0 - 1, Sm1), 0)];
    const int t0l  = tg[min(j0,     Sm1)];
    const int t1l  = tg[min(j0 + 1, Sm1)];
    const int t2l  = tg[min(j0 + 2, Sm1)];
    const int t3l  = tg[min(j0 + 3, Sm1)];
    const int t4l  = tg[min(j0 + 4, Sm1)];
    const float m1 = (j0 == 0 || t0l != tm) ? 1.f : 0.f;
    const float m3 = (t1l != t0l) ? 1.f : 0.f;
    const float m5 = (t2l != t1l) ? 1.f : 0.f;
    const float m7 = (t3l != t2l) ? 1.f : 0.f;
    const float n7 = (t4l != t3l) ? 1.f : 0.f;   // backward-only boundary gate

    const unsigned short* po_b = po + (size_t)b * T * VSZ;
    const float*          pbr  = pbf + (size_t)b * T;

    float A[8];
    int   E = 0;
    if (w == 0) {
        #pragma unroll
        for (int k = 0; k < 8; ++k) A[k] = 0.f;
        if (i == 0) A[0] = 1.f;                               // alpha init: onehot state 0
        scan_dir<0>(po_b, pbr, dF0, dF1, pF0, pF1,
                    lenD, lm1, i, m1, m3, m5, m7, n7, A, E);
    } else {
        const int tl = tlen_p[b];
        const int s1 = 2 * tl - 1, s2 = 2 * tl;               // final states
        #pragma unroll
        for (int k = 0; k < 8; ++k)
            A[k] = (8 * i + k == s1 || 8 * i + k == s2) ? 1.f : 0.f;   // beta_{len-1}
        scan_dir<1>(po_b, pbr, dB0, dB1, pB0, pB1,
                    lenD, lm1, i, m1, m3, m5, m7, n7, A, E);
        *(float4*)&bfin[8 * i]     = make_float4(A[0], A[1], A[2], A[3]);
        *(float4*)&bfin[8 * i + 4] = make_float4(A[4], A[5], A[6], A[7]);
        bein[i] = E;
    }
    __syncthreads();
    if (w == 0) {
        // total = sum_s alpha_{m-1}[s] * beta_{m-1}[s], with per-lane pow2 exponents
        float4 u0 = *(float4*)&bfin[8 * i];
        float4 u1 = *(float4*)&bfin[8 * i + 4];
        float dsum = A[0]*u0.x + A[1]*u0.y + A[2]*u0.z + A[3]*u0.w
                   + A[4]*u1.x + A[5]*u1.y + A[6]*u1.z + A[7]*u1.w;
        float li = (dsum > 0.f) ? __logf(dsum) + (float)(E + bein[i]) * LN2F : NEG;
        float mx = li;
        #pragma unroll
        for (int off = 32; off; off >>= 1) mx = fmaxf(mx, __shfl_xor(mx, off, 64));
        float ss = __expf(li - mx);
        #pragma unroll
        for (int off = 32; off; off >>= 1) ss += __shfl_xor(ss, off, 64);
        if (i == 0) out[b] = -(mx + __logf(ss));
    }
}

// ---------------------------------------------------------------------------
// Fallback (R2, known-good) if workspace is too small.
// ---------------------------------------------------------------------------
__device__ __forceinline__ void barrier_lgkm() {
    __asm__ volatile("s_waitcnt lgkmcnt(0)\n\ts_barrier" ::: "memory");
}

__global__ __launch_bounds__(256) void lse_kernel(const float* __restrict__ logits,
                                                  float* __restrict__ lse,
                                                  int nrows) {
    int row = blockIdx.x * 4 + (threadIdx.x >> 6);
    if (row >= nrows) return;
    int lane = threadIdx.x & 63;
    const float4* p = (const float4*)(logits + (size_t)row * VSZ);
    float4 x = p[lane];
    float m = fmaxf(fmaxf(x.x, x.y), fmaxf(x.z, x.w));
    #pragma unroll
    for (int off = 32; off; off >>= 1) m = fmaxf(m, __shfl_xor(m, off, 64));
    float s = __expf(x.x - m) + __expf(x.y - m) + __expf(x.z - m) + __expf(x.w - m);
    #pragma unroll
    for (int off = 32; off; off >>= 1) s += __shfl_xor(s, off, 64);
    if (lane == 0) lse[row] = m + __logf(s);
}

__device__ __forceinline__ float lae(float a, float b) {
    float mx = fmaxf(a, b);
    float mn = fminf(a, b);
    return mx + __logf(1.0f + __expf(mn - mx));
}

__global__ __launch_bounds__(256, 1) void ctc_scan_fb(const float* __restrict__ logits,
                                                      const int* __restrict__ targets,
                                                      const int* __restrict__ llen_p,
                                                      const int* __restrict__ tlen_p,
                                                      const float* __restrict__ lse,
                                                      float* __restrict__ out,
                                                      int T, int S) {
    const int b = blockIdx.x;
    const int i = threadIdx.x;
    const int len = llen_p[b];

    __shared__ float blankv[TCAP];
    __shared__ float abuf[2][256 + 2];
    __shared__ float wsum[4];

    const float* __restrict__ lgb  = logits + (size_t)b * T * VSZ;
    const float* __restrict__ lseb = lse + (size_t)b * T;

    int  lab  = 0;
    bool skip = false;
    if (i < S) {
        lab = targets[b * S + i];
        int prev = (i >= 1) ? targets[b * S + i - 1] : -1;
        skip = (lab != prev);
    }
    for (int t = i; t < len; t += 256) blankv[t] = lgb[(size_t)t * VSZ];
    if (i < 2) abuf[i][0] = NEG;
    __syncthreads();

    float aEven = (i == 0) ? 0.0f : NEG;
    float aOdd  = NEG;
    const int lm1 = len - 1;
    float v0 = lgb[(size_t)lab];
    float v1 = lgb[(size_t)min(1, lm1) * VSZ + lab];
    float v2 = lgb[(size_t)min(2, lm1) * VSZ + lab];

    for (int t = 0; t < len; ++t) {
        float v3 = lgb[(size_t)min(t + 3, lm1) * VSZ + lab];
        float blv = blankv[t];
        abuf[t & 1][i + 1] = aOdd;
        barrier_lgkm();
        float nb = abuf[t & 1][i];
        float ne = lae(aEven, nb) + blv;
        float no = lae(lae(aOdd, aEven), skip ? nb : NEG) + v0;
        aEven = ne; aOdd = no;
        v0 = v1; v1 = v2; v2 = v3;
    }

    blankv[2 * i]     = aEven;
    blankv[2 * i + 1] = aOdd;
    float part = 0.f;
    for (int t = i; t < len; t += 256) part += lseb[t];
    #pragma unroll
    for (int off = 32; off; off >>= 1) part += __shfl_xor(part, off, 64);
    if ((i & 63) == 0) wsum[i >> 6] = part;
    __syncthreads();
    if (i == 0) {
        int tl = tlen_p[b];
        float s = wsum[0] + wsum[1] + wsum[2] + wsum[3];
        out[b] = s - lae(blankv[2 * tl - 1], blankv[2 * tl]);
    }
}

// ---------------------------------------------------------------------------
extern "C" void kernel_launch(void* const* d_in, const int* in_sizes, int n_in,
                              void* d_out, int out_size, void* d_ws, size_t ws_size,
                              hipStream_t stream) {
    const float* logits  = (const float*)d_in[0];
    const int*   targets = (const int*)d_in[1];
    const int*   llen    = (const int*)d_in[2];
    const int*   tlen    = (const int*)d_in[3];
    float*       out     = (float*)d_out;

    const int B = in_sizes[2];
    const int S = in_sizes[1] / B;
    const int T = in_sizes[0] / (B * VSZ);
    const int nrows = B * T;

    const size_t need = (size_t)nrows * VSZ * sizeof(unsigned short)
                      + (size_t)nrows * sizeof(float);
    if (ws_size >= need) {
        unsigned short* po = (unsigned short*)d_ws;            // nrows*256 bf16
        float* pbf = (float*)(po + (size_t)nrows * VSZ);       // nrows f32
        dim3 grid((T + 3) / 4, B);
        prep7<<<grid, 256, 0, stream>>>(logits, targets, po, pbf, T, S);
        ctc_scan15<<<B, 128, 0, stream>>>(po, pbf, targets, llen, tlen, out, T, S);
    } else {
        float* lse = (float*)d_ws;                             // nrows f32
        lse_kernel<<<(nrows + 3) / 4, 256, 0, stream>>>(logits, lse, nrows);
        ctc_scan_fb<<<B, 256, 0, stream>>>(logits, targets, llen, tlen, lse, out, T, S);
    }
}